// Round 7
// baseline (2194.279 us; speedup 1.0000x reference)
//
#include <hip/hip_runtime.h>
#include <math.h>

typedef float4 f4;
#define NW 248
#define NB 64
#define NT 255   // ticks: window w runs ticks w..w+7; last = 247+7 = 254

__device__ __forceinline__ float sigm(float x)   { return __builtin_amdgcn_rcpf(1.0f + __expf(-x)); }
__device__ __forceinline__ float tanh_f(float x) { return 2.0f * __builtin_amdgcn_rcpf(1.0f + __expf(-2.0f * x)) - 1.0f; }

#define L8(V,P) \
  f4 V##0=(P)[0],V##1=(P)[1],V##2=(P)[2],V##3=(P)[3],V##4=(P)[4],V##5=(P)[5],V##6=(P)[6],V##7=(P)[7];

#define FMA1(acc,W,H) { f4 h_=(H); acc=fmaf((W).x,h_.x,acc); acc=fmaf((W).y,h_.y,acc); \
                        acc=fmaf((W).z,h_.z,acc); acc=fmaf((W).w,h_.w,acc); }

#define DOT8(q0,q1,q2,q3,V,HB) \
  FMA1(q0,V##0,(HB)[0]) FMA1(q1,V##1,(HB)[1]) FMA1(q2,V##2,(HB)[2]) FMA1(q3,V##3,(HB)[3]) \
  FMA1(q0,V##4,(HB)[4]) FMA1(q1,V##5,(HB)[5]) FMA1(q2,V##6,(HB)[6]) FMA1(q3,V##7,(HB)[7])

__global__ __launch_bounds__(512)
void or_lstm_tick(const float* __restrict__ traj,
                  const float* __restrict__ Wih0, const float* __restrict__ Whh0,
                  const float* __restrict__ bih0, const float* __restrict__ bhh0,
                  const float* __restrict__ Wih1, const float* __restrict__ Whh1,
                  const float* __restrict__ bih1, const float* __restrict__ bhh1,
                  const float* __restrict__ Wlin, const float* __restrict__ blin,
                  float* __restrict__ out)
{
    const int row  = blockIdx.x;
    const int tid  = threadIdx.x;       // = ((j*4)+g)*2 + half
    const int half = tid & 1;
    const int rr   = tid >> 1;          // 0..255
    const int j    = rr >> 2;           // h index 0..63
    const int g    = rr & 3;            // gate 0=i,1=f,2=g(tanh),3=o
    const int r    = g * 64 + j;
    const int ko   = half * 32;

    __shared__ __align__(16) float trajS[256 * 4];
    __shared__ __align__(16) float H0[2][8][64];   // [phase][slot][j]
    __shared__ __align__(16) float H1[2][8][64];
    __shared__ float ring[8][2];                   // out[w] at ring[w&7]

    if (tid < 256)
        ((f4*)trajS)[tid] = ((const f4*)(traj + (size_t)row * 256 * 4))[tid];

    // per-thread weight half-rows (compiler keeps or reloads from L1 — either
    // is fine now: 8 independent slots hide the latency)
    const f4* pA = (const f4*)(Whh0 + r * 64 + ko);
    const f4* pB = (const f4*)(Wih1 + r * 64 + ko);
    const f4* pC = (const f4*)(Whh1 + r * 64 + ko);
    L8(A, pA)
    L8(Bv, pB)
    L8(Cv, pC)
    const float wiA = Wih0[r * 4 + 2 * half];
    const float wiB = Wih0[r * 4 + 2 * half + 1];
    const float bb0 = half ? 0.f : (bih0[r] + bhh0[r]);
    const float bb1 = half ? 0.f : (bih1[r] + bhh1[r]);
    float wl0 = 0.f, wl1 = 0.f;
    if (tid < 64) { wl0 = Wlin[tid]; wl1 = Wlin[64 + tid]; }
    const float bl0 = blin[0], bl1 = blin[1];

    const int lane = tid & 63;
    const int gsel = (lane & ~7) + half;   // gate G of own half at lane gsel + 2G

    float cc0[8], cc1[8];
#pragma unroll
    for (int k = 0; k < 8; ++k) { cc0[k] = 0.f; cc1[k] = 0.f; }

    __syncthreads();

    for (int t = 0; t < NT; ++t) {
        const int ps = t & 1, pn = ps ^ 1;

        // ================= PHASE A: layer 0, all slots =================
#pragma unroll
        for (int k = 0; k < 8; ++k) {
            if (t >= k && t <= 247 + k) {
                const int s = (t - k) & 7;
                const int w = k + ((t - k) & ~7);

                // ---- input features (verbatim R6-verified indexing) ----
                float x0, x1, x2, x3;
                if (w == 0) {
                    x0 = trajS[s*4+0]; x1 = trajS[s*4+1]; x2 = trajS[s*4+2]; x3 = trajS[s*4+3];
                } else if (w < 8) {
                    if (s < 8 - w) {
                        const int tt = w + s;
                        x0 = trajS[tt*4+0]; x1 = trajS[tt*4+1]; x2 = trajS[tt*4+2]; x3 = trajS[tt*4+3];
                    } else {
                        const int tc = 2*w + s - 1;
                        const int jo = (t - 8) & 7;
                        x0 = trajS[tc*4+0]; x1 = trajS[tc*4+1];
                        x2 = ring[jo][0];   x3 = ring[jo][1];
                    }
                } else {
                    const int jo = (t - 8) & 7;
                    x0 = trajS[t*4+0]; x1 = trajS[t*4+1];
                    x2 = ring[jo][0];  x3 = ring[jo][1];
                }
                const float xa = half ? x2 : x0;
                const float xb = half ? x3 : x1;

                float q0 = fmaf(wiA, xa, fmaf(wiB, xb, bb0));
                float q1 = 0.f, q2 = 0.f, q3 = 0.f;
                if (s) {                       // s==0: h_prev = 0, skip dot
                    const f4* H = (const f4*)(&H0[ps][k][ko]);
                    DOT8(q0, q1, q2, q3, A, H)
                }
                float acc = (q0 + q2) + (q1 + q3);
                acc += __shfl_xor(acc, 1, 64);
                const float a = (g == 2) ? tanh_f(acc) : sigm(acc);
                const float ai = __shfl(a, gsel + 0, 64);
                const float af = __shfl(a, gsel + 2, 64);
                const float ag = __shfl(a, gsel + 4, 64);
                const float ao = __shfl(a, gsel + 6, 64);
                const float cp = s ? cc0[k] : 0.f;
                cc0[k] = af * cp + ai * ag;
                const float h0v = ao * tanh_f(cc0[k]);
                if (g == 0 && half == 0) H0[pn][k][j] = h0v;
            }
        }
        __syncthreads();   // barrier 1: H0[pn] complete

        // ================= PHASE B: layer 1, all slots =================
#pragma unroll
        for (int k = 0; k < 8; ++k) {
            if (t >= k && t <= 247 + k) {
                const int s = (t - k) & 7;
                float q0 = bb1, q1 = 0.f, q2 = 0.f, q3 = 0.f;
                const f4* Hx = (const f4*)(&H0[pn][k][ko]);
                DOT8(q0, q1, q2, q3, Bv, Hx)
                if (s) {
                    const f4* Hh = (const f4*)(&H1[ps][k][ko]);
                    DOT8(q0, q1, q2, q3, Cv, Hh)
                }
                float acc = (q0 + q2) + (q1 + q3);
                acc += __shfl_xor(acc, 1, 64);
                const float a = (g == 2) ? tanh_f(acc) : sigm(acc);
                const float ai = __shfl(a, gsel + 0, 64);
                const float af = __shfl(a, gsel + 2, 64);
                const float ag = __shfl(a, gsel + 4, 64);
                const float ao = __shfl(a, gsel + 6, 64);
                const float cp = s ? cc1[k] : 0.f;
                cc1[k] = af * cp + ai * ag;
                const float h1v = ao * tanh_f(cc1[k]);
                if (g == 0 && half == 0) H1[pn][k][j] = h1v;
            }
        }
        __syncthreads();   // barrier 2: H1[pn] complete

        // ================= PHASE C: epilogue of finishing window =================
        if (t >= 7 && tid < 64) {
            const int kf = (t + 1) & 7;        // slot with s==7 this tick
            const int wf = t - 7;
            const float hv = H1[pn][kf][tid];
            float p0 = wl0 * hv;
            float p1 = wl1 * hv;
#pragma unroll
            for (int off = 32; off > 0; off >>= 1) {
                p0 += __shfl_down(p0, off);
                p1 += __shfl_down(p1, off);
            }
            if (tid == 0) {
                float prev0, prev1;
                if (wf == 0) { prev0 = trajS[7*4+2];       prev1 = trajS[7*4+3]; }
                else         { prev0 = ring[(wf-1)&7][0];  prev1 = ring[(wf-1)&7][1]; }
                const float o0 = prev0 + p0 + bl0;
                const float o1 = prev1 + p1 + bl1;
                ring[wf & 7][0] = o0; ring[wf & 7][1] = o1;
                out[((size_t)row * NW + wf) * 2 + 0] = o0;
                out[((size_t)row * NW + wf) * 2 + 1] = o1;
            }
        }
        if (t == NT - 1 && g == 0 && half == 0) {   // final h/c of window 247 (slot 7)
            float* hn = out + (size_t)NB * NW * 2;
            float* cn = hn + 2 * NB * 64;
            hn[(0 * NB + row) * 64 + j] = H0[pn][7][j];
            hn[(1 * NB + row) * 64 + j] = H1[pn][7][j];
            cn[(0 * NB + row) * 64 + j] = cc0[7];
            cn[(1 * NB + row) * 64 + j] = cc1[7];
        }
        __syncthreads();   // barrier 3: ring visible to next tick's phase A
    }
}

extern "C" void kernel_launch(void* const* d_in, const int* in_sizes, int n_in,
                              void* d_out, int out_size, void* d_ws, size_t ws_size,
                              hipStream_t stream) {
    const float* traj = (const float*)d_in[0];
    const float* Wih0 = (const float*)d_in[1];
    const float* Whh0 = (const float*)d_in[2];
    const float* bih0 = (const float*)d_in[3];
    const float* bhh0 = (const float*)d_in[4];
    const float* Wih1 = (const float*)d_in[5];
    const float* Whh1 = (const float*)d_in[6];
    const float* bih1 = (const float*)d_in[7];
    const float* bhh1 = (const float*)d_in[8];
    const float* Wlin = (const float*)d_in[9];
    const float* blin = (const float*)d_in[10];
    float* out = (float*)d_out;

    or_lstm_tick<<<dim3(NB), dim3(512), 0, stream>>>(
        traj, Wih0, Whh0, bih0, bhh0, Wih1, Whh1, bih1, bhh1, Wlin, blin, out);
}